// Round 8
// baseline (225.624 us; speedup 1.0000x reference)
//
#include <hip/hip_runtime.h>
#include <hip/hip_bf16.h>
#include <math.h>

#define M_  4
#define B_  2048
#define K_  32
#define D_  256
#define DZ_ 128
#define PAD 68

#define K2_SMEM_FLOATS (4 * 8192 + 32)
#define K2_SMEM_BYTES  (K2_SMEM_FLOATS * 4)

// ---------------------------------------------------------------------------
// K0: Wqk[m][z][d] = sum_e W_Q[z][e] * W_K[m][d][e]   (fold W_Q into W_K)
// ---------------------------------------------------------------------------
__global__ void __launch_bounds__(256) k0_wqk(const float* __restrict__ W_Q,
                                              const float* __restrict__ W_K,
                                              float* __restrict__ Wqk) {
    int mz = blockIdx.x;
    int m = mz >> 7, z = mz & 127;
    int d = threadIdx.x;
    __shared__ float wq[D_];
    wq[d] = W_Q[z * D_ + d];
    __syncthreads();
    const float* wk = W_K + (m * D_ + d) * D_;
    float acc = 0.f;
#pragma unroll 8
    for (int e = 0; e < D_; ++e) acc = fmaf(wq[e], wk[e], acc);
    Wqk[(m * DZ_ + z) * D_ + d] = acc;
}

// ---------------------------------------------------------------------------
// K1: Qk[m][b][d] = sum_z z_anc[b][z] * Wqk[m][z][d]
// ---------------------------------------------------------------------------
__global__ void __launch_bounds__(256) k1_qk(const float* __restrict__ z_anc,
                                             const float* __restrict__ Wqk,
                                             float* __restrict__ Qk) {
    int m = blockIdx.z;
    int b0 = blockIdx.x * 64, d0 = blockIdx.y * 64;
    int t = threadIdx.x, tx = t & 15, ty = t >> 4;
    __shared__ float As[64 * PAD];
    __shared__ float Bs[64 * PAD];
    float c[4][4] = {};
    for (int kc = 0; kc < DZ_; kc += 64) {
#pragma unroll
        for (int it = 0; it < 4; ++it) {
            int s = it * 256 + t, bi = s >> 4, k4 = (s & 15) * 4;
            *(float4*)&As[bi * PAD + k4] =
                *(const float4*)&z_anc[(b0 + bi) * DZ_ + kc + k4];
        }
#pragma unroll
        for (int it = 0; it < 4; ++it) {
            int s = it * 256 + t, kk = s >> 4, d4 = (s & 15) * 4;
            *(float4*)&Bs[kk * PAD + d4] =
                *(const float4*)&Wqk[(m * DZ_ + kc + kk) * D_ + d0 + d4];
        }
        __syncthreads();
#pragma unroll 4
        for (int kk = 0; kk < 64; ++kk) {
            float a[4];
#pragma unroll
            for (int i = 0; i < 4; ++i) a[i] = As[(ty * 4 + i) * PAD + kk];
            float4 b4 = *(const float4*)&Bs[kk * PAD + tx * 4];
#pragma unroll
            for (int i = 0; i < 4; ++i) {
                c[i][0] = fmaf(a[i], b4.x, c[i][0]);
                c[i][1] = fmaf(a[i], b4.y, c[i][1]);
                c[i][2] = fmaf(a[i], b4.z, c[i][2]);
                c[i][3] = fmaf(a[i], b4.w, c[i][3]);
            }
        }
        __syncthreads();
    }
#pragma unroll
    for (int i = 0; i < 4; ++i) {
        float4 v = make_float4(c[i][0], c[i][1], c[i][2], c[i][3]);
        *(float4*)&Qk[(m * B_ + b0 + ty * 4 + i) * D_ + d0 + tx * 4] = v;
    }
}

__device__ __forceinline__ void gl_lds16(const float* g, float* lds) {
    __builtin_amdgcn_global_load_lds(
        (const __attribute__((address_space(1))) void*)g,
        (__attribute__((address_space(3))) void*)lds, 16, 0, 0);
}

// ---------------------------------------------------------------------------
// K2: max-duty-cycle pipeline. 256 blocks x 512 threads (1/CU), 128KB LDS
// double-buffer, 32 items/block. Per iteration:
//   A: issue 8 DMA(nxt) then 4 reg loads(nxt)      [64KB always in flight]
//   vmcnt(12): waits ONLY cur-tile DMA (12 newest = nxt's ops stay live;
//              no fresh-load latency stall — R7's bug)
//   C: scores — wave w reads EXACTLY the rows it DMA'd (own vmcnt covers
//      them; no barrier needed before C — R7 had one)
//   B1: lgkmcnt(0)+barrier (sc[] ready)
//   D/E: softmax (per-wave, registers) + weighted sums + stores
//   B2: barrier (all reads of cur buffer done before next A overwrites it)
// 2 barriers/iter vs R7's 3; fetch never idles.
// ---------------------------------------------------------------------------
__global__ void __launch_bounds__(512, 1) k2_main(
    const float* __restrict__ h_nei, const float* __restrict__ ew_anc,
    const float* __restrict__ vmask, const float* __restrict__ lbl_delta,
    const float* __restrict__ lbl_w, const float* __restrict__ Qk,
    const float* __restrict__ log_vw,
    float* __restrict__ hbar, float* __restrict__ lblp)
{
    extern __shared__ float smem[];
    // layout: h0[8192] | h1[8192] | l0[8192] | l1[8192] | sc[32]
    float* sc = smem + 32768;

    int t = threadIdx.x, w = t >> 6, l = t & 63;
    int base = blockIdx.x * 32;

    // vw = softmax(log_vw): once, uniform
    float lv0 = log_vw[0], lv1 = log_vw[1], lv2 = log_vw[2], lv3 = log_vw[3];
    float mv = fmaxf(fmaxf(lv0, lv1), fmaxf(lv2, lv3));
    float e0 = expf(lv0 - mv), e1 = expf(lv1 - mv),
          e2 = expf(lv2 - mv), e3 = expf(lv3 - mv);
    float den = e0 + e1 + e2 + e3;
    float vw0 = e0 / den, vw1 = e1 / den, vw2 = e2 / den, vw3 = e3 / den;

    // --- prologue: DMA item 0, then its reg loads ---
    float4 q4c; float ewc, lwc, vmc;
    {
        int g = base; int b = g >> 2, m = g & 3;
        const float* hb  = h_nei + (size_t)(m * B_ + b) * (K_ * D_);
        const float* ldb = lbl_delta + (size_t)b * (K_ * M_ * D_) + m * D_;
#pragma unroll
        for (int j = 0; j < 4; ++j) {
            int k = w * 4 + j;
            gl_lds16(hb + k * D_ + 4 * l, smem + k * D_);
            gl_lds16(ldb + (size_t)k * (M_ * D_) + 4 * l, smem + 16384 + k * D_);
        }
        q4c = *(const float4*)&Qk[(m * B_ + b) * D_ + 4 * l];
        int idx = (b * K_ + (l & 31)) * M_ + m;
        ewc = ew_anc[idx]; lwc = lbl_w[idx]; vmc = vmask[idx];
    }

    for (int it = 0; it < 32; ++it) {
        int curo = (it & 1) ? 8192 : 0;
        int nxto = curo ^ 8192;
        int nxt = (it + 1) & 31;   // last iter: harmless wrap prefetch

        // --- A: DMA(nxt) FIRST, then reg loads(nxt) ---
        float4 q4n; float ewn, lwn, vmn;
        {
            int g = base + nxt; int b = g >> 2, m = g & 3;
            const float* hb  = h_nei + (size_t)(m * B_ + b) * (K_ * D_);
            const float* ldb = lbl_delta + (size_t)b * (K_ * M_ * D_) + m * D_;
#pragma unroll
            for (int j = 0; j < 4; ++j) {
                int k = w * 4 + j;
                gl_lds16(hb + k * D_ + 4 * l, smem + nxto + k * D_);
                gl_lds16(ldb + (size_t)k * (M_ * D_) + 4 * l,
                         smem + 16384 + nxto + k * D_);
            }
            q4n = *(const float4*)&Qk[(m * B_ + b) * D_ + 4 * l];
            int idx = (b * K_ + (l & 31)) * M_ + m;
            ewn = ew_anc[idx]; lwn = lbl_w[idx]; vmn = vmask[idx];
        }

        // --- wait cur DMA only (12 newest = nxt's 8 DMA + 4 reg stay) ---
        asm volatile("s_waitcnt vmcnt(12)" ::: "memory");
        __builtin_amdgcn_sched_barrier(0);

        const float* hd  = smem + curo;
        const float* ld_ = smem + 16384 + curo;

        // --- C: scores — wave w owns rows it DMA'd (no barrier needed) ---
#pragma unroll
        for (int j = 0; j < 4; ++j) {
            int k = w * 4 + j;
            float4 h4 = *(const float4*)&hd[k * D_ + 4 * l];
            float v = h4.x * q4c.x + h4.y * q4c.y + h4.z * q4c.z + h4.w * q4c.w;
            v += __shfl_xor(v, 32); v += __shfl_xor(v, 16); v += __shfl_xor(v, 8);
            v += __shfl_xor(v, 4);  v += __shfl_xor(v, 2);  v += __shfl_xor(v, 1);
            if (l == 0) sc[k] = v;
        }

        // --- B1: sc[] visible to all waves ---
        asm volatile("s_waitcnt lgkmcnt(0)" ::: "memory");
        __builtin_amdgcn_sched_barrier(0);
        __builtin_amdgcn_s_barrier();

        // --- D: per-wave redundant softmax (at stays in registers) ---
        int g = base + it; int b = g >> 2, m = g & 3;
        float vw_m = (m == 0) ? vw0 : (m == 1) ? vw1 : (m == 2) ? vw2 : vw3;
        float s = sc[l & 31] * 0.0625f + logf(ewc + 1e-6f) + lwc;
        if (vmc == 0.f) s = -1e9f;
        float mx = s;
        mx = fmaxf(mx, __shfl_xor(mx, 16)); mx = fmaxf(mx, __shfl_xor(mx, 8));
        mx = fmaxf(mx, __shfl_xor(mx, 4));  mx = fmaxf(mx, __shfl_xor(mx, 2));
        mx = fmaxf(mx, __shfl_xor(mx, 1));
        float ee = expf(s - mx);
        float dsum = ee;
        dsum += __shfl_xor(dsum, 16); dsum += __shfl_xor(dsum, 8);
        dsum += __shfl_xor(dsum, 4);  dsum += __shfl_xor(dsum, 2);
        dsum += __shfl_xor(dsum, 1);
        float atv = (ee / dsum) * vw_m;   // lane l holds at[l&31]

        // --- E: weighted sums — waves 0-3: h cols; waves 4-7: lbl cols ---
        float acc = 0.f;
        const float* src = (t < 256) ? hd : ld_;
        int col = t & 255;
#pragma unroll
        for (int k = 0; k < K_; ++k) {
            float a = __int_as_float(
                __builtin_amdgcn_readlane(__float_as_int(atv), k));
            acc = fmaf(a, src[k * D_ + col], acc);
        }
        if (t < 256) hbar[(size_t)b * (M_ * D_) + m * D_ + col] = acc;
        else         lblp[((size_t)m * B_ + b) * D_ + col] = acc;

        // rotate prefetched registers
        q4c = q4n; ewc = ewn; lwc = lwn; vmc = vmn;

        // --- B2: all reads of cur buffer done before next A overwrites ---
        __builtin_amdgcn_sched_barrier(0);
        __builtin_amdgcn_s_barrier();
    }
}

// ---------------------------------------------------------------------------
// K3: out[b][e] = sum_kk hbar[b][kk]*W_Vflat[kk][e] + sum_m lblp[m][b][e]
// ---------------------------------------------------------------------------
__global__ void __launch_bounds__(256) k3_gemm(const float* __restrict__ hbar,
                                               const float* __restrict__ W_V,
                                               const float* __restrict__ lblp,
                                               float* __restrict__ out) {
    int b0 = blockIdx.x * 16, e0 = blockIdx.y * 64;
    int t = threadIdx.x, tx = t & 15, ty = t >> 4;
    __shared__ float As[16 * PAD];
    __shared__ float Bs[64 * PAD];
    float c0 = 0.f, c1 = 0.f, c2 = 0.f, c3 = 0.f;
    for (int kc = 0; kc < M_ * D_; kc += 64) {
        {
            int bi = t >> 4, k4 = (t & 15) * 4;
            *(float4*)&As[bi * PAD + k4] =
                *(const float4*)&hbar[(size_t)(b0 + bi) * (M_ * D_) + kc + k4];
        }
#pragma unroll
        for (int it = 0; it < 4; ++it) {
            int s = it * 256 + t, kk = s >> 4, e4 = (s & 15) * 4;
            *(float4*)&Bs[kk * PAD + e4] =
                *(const float4*)&W_V[(size_t)(kc + kk) * D_ + e0 + e4];
        }
        __syncthreads();
#pragma unroll 4
        for (int kk = 0; kk < 64; ++kk) {
            float a0 = As[ty * PAD + kk];
            float4 b4 = *(const float4*)&Bs[kk * PAD + tx * 4];
            c0 = fmaf(a0, b4.x, c0);
            c1 = fmaf(a0, b4.y, c1);
            c2 = fmaf(a0, b4.z, c2);
            c3 = fmaf(a0, b4.w, c3);
        }
        __syncthreads();
    }
    int row = b0 + ty, col = e0 + tx * 4;
    float4 s = make_float4(c0, c1, c2, c3);
#pragma unroll
    for (int mm = 0; mm < 4; ++mm) {
        float4 lp = *(const float4*)&lblp[((size_t)mm * B_ + row) * D_ + col];
        s.x += lp.x; s.y += lp.y; s.z += lp.z; s.w += lp.w;
    }
    *(float4*)&out[(size_t)row * D_ + col] = s;
}

// ---------------------------------------------------------------------------
extern "C" void kernel_launch(void* const* d_in, const int* in_sizes, int n_in,
                              void* d_out, int out_size, void* d_ws, size_t ws_size,
                              hipStream_t stream) {
    const float* h_nei     = (const float*)d_in[0];
    const float* ew_anc    = (const float*)d_in[1];
    const float* vmask     = (const float*)d_in[2];
    const float* z_anc     = (const float*)d_in[3];
    const float* lbl_delta = (const float*)d_in[4];
    const float* lbl_w     = (const float*)d_in[5];
    const float* W_Q       = (const float*)d_in[6];
    const float* W_K       = (const float*)d_in[7];
    const float* W_V       = (const float*)d_in[8];
    const float* log_vw    = (const float*)d_in[9];
    float* out = (float*)d_out;

    // ws layout (floats):
    //   Wqk[4*128*256] | Qk[4*2048*256] | hbar[2048*1024] | lblp[4*2048*256]
    float* ws   = (float*)d_ws;
    float* Wqk  = ws;
    float* Qk   = Wqk + (M_ * DZ_ * D_);
    float* hbar = Qk + (M_ * B_ * D_);
    float* lblp = hbar + (B_ * M_ * D_);

    // allow 128KB dynamic LDS for k2 (host-side, capture-safe, idempotent)
    (void)hipFuncSetAttribute((const void*)k2_main,
                              hipFuncAttributeMaxDynamicSharedMemorySize,
                              K2_SMEM_BYTES);

    k0_wqk<<<M_ * DZ_, 256, 0, stream>>>(W_Q, W_K, Wqk);

    dim3 g1(B_ / 64, D_ / 64, M_);
    k1_qk<<<g1, 256, 0, stream>>>(z_anc, Wqk, Qk);

    k2_main<<<256, 512, K2_SMEM_BYTES, stream>>>(
        h_nei, ew_anc, vmask, lbl_delta, lbl_w, Qk, log_vw, hbar, lblp);

    dim3 g3(B_ / 16, D_ / 64);
    k3_gemm<<<g3, 256, 0, stream>>>(hbar, W_V, lblp, out);
}

// Round 9
// 180.385 us; speedup vs baseline: 1.2508x; 1.2508x over previous
//
#include <hip/hip_runtime.h>
#include <hip/hip_bf16.h>
#include <math.h>

#define M_  4
#define B_  2048
#define K_  32
#define D_  256
#define DZ_ 128
#define PAD 68

// ---------------------------------------------------------------------------
// K0: Wqk[m][z][d] = sum_e W_Q[z][e] * W_K[m][d][e]
// ---------------------------------------------------------------------------
__global__ void __launch_bounds__(256) k0_wqk(const float* __restrict__ W_Q,
                                              const float* __restrict__ W_K,
                                              float* __restrict__ Wqk) {
    int mz = blockIdx.x;
    int m = mz >> 7, z = mz & 127;
    int d = threadIdx.x;
    __shared__ float wq[D_];
    wq[d] = W_Q[z * D_ + d];
    __syncthreads();
    const float* wk = W_K + (m * D_ + d) * D_;
    float acc = 0.f;
#pragma unroll 8
    for (int e = 0; e < D_; ++e) acc = fmaf(wq[e], wk[e], acc);
    Wqk[(m * DZ_ + z) * D_ + d] = acc;
}

// ---------------------------------------------------------------------------
// K1: Qk[m][b][d] = sum_z z_anc[b][z] * Wqk[m][z][d]
// ---------------------------------------------------------------------------
__global__ void __launch_bounds__(256) k1_qk(const float* __restrict__ z_anc,
                                             const float* __restrict__ Wqk,
                                             float* __restrict__ Qk) {
    int m = blockIdx.z;
    int b0 = blockIdx.x * 64, d0 = blockIdx.y * 64;
    int t = threadIdx.x, tx = t & 15, ty = t >> 4;
    __shared__ float As[64 * PAD];
    __shared__ float Bs[64 * PAD];
    float c[4][4] = {};
    for (int kc = 0; kc < DZ_; kc += 64) {
#pragma unroll
        for (int it = 0; it < 4; ++it) {
            int s = it * 256 + t, bi = s >> 4, k4 = (s & 15) * 4;
            *(float4*)&As[bi * PAD + k4] =
                *(const float4*)&z_anc[(b0 + bi) * DZ_ + kc + k4];
        }
#pragma unroll
        for (int it = 0; it < 4; ++it) {
            int s = it * 256 + t, kk = s >> 4, d4 = (s & 15) * 4;
            *(float4*)&Bs[kk * PAD + d4] =
                *(const float4*)&Wqk[(m * DZ_ + kc + kk) * D_ + d0 + d4];
        }
        __syncthreads();
#pragma unroll 4
        for (int kk = 0; kk < 64; ++kk) {
            float a[4];
#pragma unroll
            for (int i = 0; i < 4; ++i) a[i] = As[(ty * 4 + i) * PAD + kk];
            float4 b4 = *(const float4*)&Bs[kk * PAD + tx * 4];
#pragma unroll
            for (int i = 0; i < 4; ++i) {
                c[i][0] = fmaf(a[i], b4.x, c[i][0]);
                c[i][1] = fmaf(a[i], b4.y, c[i][1]);
                c[i][2] = fmaf(a[i], b4.z, c[i][2]);
                c[i][3] = fmaf(a[i], b4.w, c[i][3]);
            }
        }
        __syncthreads();
    }
#pragma unroll
    for (int i = 0; i < 4; ++i) {
        float4 v = make_float4(c[i][0], c[i][1], c[i][2], c[i][3]);
        *(float4*)&Qk[(m * B_ + b0 + ty * 4 + i) * D_ + d0 + tx * 4] = v;
    }
}

__device__ __forceinline__ void gl_lds16(const float* g, float* lds) {
    __builtin_amdgcn_global_load_lds(
        (const __attribute__((address_space(1))) void*)g,
        (__attribute__((address_space(3))) void*)lds, 16, 0, 0);
}

// ---------------------------------------------------------------------------
// K2H: h-stream only. One block per (m,b), m-MAJOR grid (consecutive blocks
// stream consecutive h_nei addresses). Reads contiguous 32KB tile via DMA,
// computes scores+softmax, writes hbar (weighted h sum) and at[] (weights,
// vw folded) for K2L. 33KB LDS -> 4 blocks/CU.
// ---------------------------------------------------------------------------
__global__ void __launch_bounds__(256) k2h(
    const float* __restrict__ h_nei, const float* __restrict__ ew_anc,
    const float* __restrict__ vmask, const float* __restrict__ lbl_w,
    const float* __restrict__ Qk, const float* __restrict__ log_vw,
    float* __restrict__ hbar, float* __restrict__ at_ws)
{
    int bx = blockIdx.x;
    int b = bx & (B_ - 1), m = bx >> 11;
    int t = threadIdx.x, w = t >> 6, l = t & 63;
    __shared__ float hs[K_ * D_];   // 32 KB
    __shared__ float sc[K_], at_l[K_];

    // DMA: wave w rows k=w*8..w*8+7; global offset == LDS offset (linear)
    const float* hb = h_nei + (size_t)(m * B_ + b) * (K_ * D_);
#pragma unroll
    for (int j = 0; j < 8; ++j) {
        int k = w * 8 + j;
        gl_lds16(hb + k * D_ + 4 * l, hs + k * D_);
    }
    // overlapped small loads while DMA in flight
    float4 q4 = *(const float4*)&Qk[(m * B_ + b) * D_ + 4 * l];
    int idx = (b * K_ + (l & 31)) * M_ + m;
    float ew_v = ew_anc[idx], lw_v = lbl_w[idx], vm_v = vmask[idx];
    float lv0 = log_vw[0], lv1 = log_vw[1], lv2 = log_vw[2], lv3 = log_vw[3];
    float mv = fmaxf(fmaxf(lv0, lv1), fmaxf(lv2, lv3));
    float e0 = expf(lv0 - mv), e1 = expf(lv1 - mv),
          e2 = expf(lv2 - mv), e3 = expf(lv3 - mv);
    float vw_m = ((m == 0) ? e0 : (m == 1) ? e1 : (m == 2) ? e2 : e3)
                 / (e0 + e1 + e2 + e3);

    __syncthreads();   // drains DMA (vmcnt 0) + LDS visible

    // scores: wave w owns rows w*8+j
#pragma unroll
    for (int j = 0; j < 8; ++j) {
        int k = w * 8 + j;
        float4 h4 = *(const float4*)&hs[k * D_ + 4 * l];
        float v = h4.x * q4.x + h4.y * q4.y + h4.z * q4.z + h4.w * q4.w;
        v += __shfl_xor(v, 32); v += __shfl_xor(v, 16); v += __shfl_xor(v, 8);
        v += __shfl_xor(v, 4);  v += __shfl_xor(v, 2);  v += __shfl_xor(v, 1);
        if (l == 0) sc[k] = v;
    }
    __syncthreads();

    // softmax (redundant per wave, 32-lane groups)
    float s = (vm_v == 0.f) ? -1e9f
                            : sc[l & 31] * 0.0625f + logf(ew_v + 1e-6f) + lw_v;
    float mx = s;
    mx = fmaxf(mx, __shfl_xor(mx, 16)); mx = fmaxf(mx, __shfl_xor(mx, 8));
    mx = fmaxf(mx, __shfl_xor(mx, 4));  mx = fmaxf(mx, __shfl_xor(mx, 2));
    mx = fmaxf(mx, __shfl_xor(mx, 1));
    float ee = expf(s - mx);
    float dsum = ee;
    dsum += __shfl_xor(dsum, 16); dsum += __shfl_xor(dsum, 8);
    dsum += __shfl_xor(dsum, 4);  dsum += __shfl_xor(dsum, 2);
    dsum += __shfl_xor(dsum, 1);
    float atv = (ee / dsum) * vw_m;

    if (t < K_) {
        at_l[t] = atv;
        at_ws[(size_t)(m * B_ + b) * K_ + t] = atv;   // for K2L
    }
    __syncthreads();

    // hbar: thread t owns column t
    float acc = 0.f;
#pragma unroll 8
    for (int k = 0; k < K_; ++k) acc = fmaf(at_l[k], hs[k * D_ + t], acc);
    hbar[(size_t)b * (M_ * D_) + m * D_ + t] = acc;
}

// ---------------------------------------------------------------------------
// K2L: lbl-stream only. One block per (b, k-half): reads a fully CONTIGUOUS
// 64KB chunk of lbl_delta[b] (natural [k][m][d] layout, wave rows are
// sequential 1KB pieces) via DMA, applies at_ws weights, writes split-k
// partials lblp2[kh][m][b][d]. 64KB LDS -> 2 blocks/CU.
// ---------------------------------------------------------------------------
__global__ void __launch_bounds__(512) k2l(
    const float* __restrict__ lbl_delta, const float* __restrict__ at_ws,
    float* __restrict__ lblp2)
{
    extern __shared__ float smem2[];      // ls[16*M_*D_] = 64KB | at_l[64]
    float* ls = smem2;
    float* at_l = smem2 + 16 * M_ * D_;

    int bx = blockIdx.x;
    int b = bx >> 1, kh = bx & 1;
    int t = threadIdx.x, w = t >> 6, l = t & 63;

    // DMA: 64 rows of 1KB; wave w rows r=w*8..w*8+7; global == LDS (linear)
    const float* ldb = lbl_delta + (size_t)b * (K_ * M_ * D_)
                                 + (size_t)kh * 16 * M_ * D_;
#pragma unroll
    for (int j = 0; j < 8; ++j) {
        int r = w * 8 + j;
        gl_lds16(ldb + r * D_ + 4 * l, ls + r * D_);
    }
    // weights: 64 values (4m x 16k) loaded by threads 0..63
    if (t < 64) {
        int m = t >> 4, kk = t & 15;
        at_l[t] = at_ws[(size_t)(m * B_ + b) * K_ + kh * 16 + kk];
    }
    __syncthreads();   // drains DMA

    // weighted sum: thread t owns (m = t>>7, d = t&127 and d+128)
    int m = t >> 7, d = t & 127;
    float a1 = 0.f, a2 = 0.f;
#pragma unroll 8
    for (int kk = 0; kk < 16; ++kk) {
        float a = at_l[m * 16 + kk];              // wave-uniform broadcast
        int base = (kk * M_ + m) * D_;
        a1 = fmaf(a, ls[base + d], a1);
        a2 = fmaf(a, ls[base + 128 + d], a2);
    }
    size_t o = ((size_t)(kh * M_ + m) * B_ + b) * D_;
    lblp2[o + d] = a1;
    lblp2[o + 128 + d] = a2;
}

// ---------------------------------------------------------------------------
// K3: out[b][e] = sum_kk hbar[b][kk]*W_Vflat[kk][e] + sum_{kh,m} lblp2[...]
// ---------------------------------------------------------------------------
__global__ void __launch_bounds__(256) k3_gemm(const float* __restrict__ hbar,
                                               const float* __restrict__ W_V,
                                               const float* __restrict__ lblp2,
                                               float* __restrict__ out) {
    int b0 = blockIdx.x * 16, e0 = blockIdx.y * 64;
    int t = threadIdx.x, tx = t & 15, ty = t >> 4;
    __shared__ float As[16 * PAD];
    __shared__ float Bs[64 * PAD];
    float c0 = 0.f, c1 = 0.f, c2 = 0.f, c3 = 0.f;
    for (int kc = 0; kc < M_ * D_; kc += 64) {
        {
            int bi = t >> 4, k4 = (t & 15) * 4;
            *(float4*)&As[bi * PAD + k4] =
                *(const float4*)&hbar[(size_t)(b0 + bi) * (M_ * D_) + kc + k4];
        }
#pragma unroll
        for (int it = 0; it < 4; ++it) {
            int s = it * 256 + t, kk = s >> 4, e4 = (s & 15) * 4;
            *(float4*)&Bs[kk * PAD + e4] =
                *(const float4*)&W_V[(size_t)(kc + kk) * D_ + e0 + e4];
        }
        __syncthreads();
#pragma unroll 4
        for (int kk = 0; kk < 64; ++kk) {
            float a0 = As[ty * PAD + kk];
            float4 b4 = *(const float4*)&Bs[kk * PAD + tx * 4];
            c0 = fmaf(a0, b4.x, c0);
            c1 = fmaf(a0, b4.y, c1);
            c2 = fmaf(a0, b4.z, c2);
            c3 = fmaf(a0, b4.w, c3);
        }
        __syncthreads();
    }
    int row = b0 + ty, col = e0 + tx * 4;
    float4 s = make_float4(c0, c1, c2, c3);
#pragma unroll
    for (int q = 0; q < 8; ++q) {
        float4 lp = *(const float4*)&lblp2[((size_t)q * B_ + row) * D_ + col];
        s.x += lp.x; s.y += lp.y; s.z += lp.z; s.w += lp.w;
    }
    *(float4*)&out[(size_t)row * D_ + col] = s;
}

// ---------------------------------------------------------------------------
extern "C" void kernel_launch(void* const* d_in, const int* in_sizes, int n_in,
                              void* d_out, int out_size, void* d_ws, size_t ws_size,
                              hipStream_t stream) {
    const float* h_nei     = (const float*)d_in[0];
    const float* ew_anc    = (const float*)d_in[1];
    const float* vmask     = (const float*)d_in[2];
    const float* z_anc     = (const float*)d_in[3];
    const float* lbl_delta = (const float*)d_in[4];
    const float* lbl_w     = (const float*)d_in[5];
    const float* W_Q       = (const float*)d_in[6];
    const float* W_K       = (const float*)d_in[7];
    const float* W_V       = (const float*)d_in[8];
    const float* log_vw    = (const float*)d_in[9];
    float* out = (float*)d_out;

    // ws (floats): Wqk[131072] | Qk[2097152] | hbar[2097152] |
    //              at_ws[262144] | lblp2[2*4*2048*256 = 4194304]
    float* ws    = (float*)d_ws;
    float* Wqk   = ws;
    float* Qk    = Wqk + (M_ * DZ_ * D_);
    float* hbar  = Qk + (M_ * B_ * D_);
    float* at_ws = hbar + (B_ * M_ * D_);
    float* lblp2 = at_ws + (M_ * B_ * K_);

    (void)hipFuncSetAttribute((const void*)k2l,
                              hipFuncAttributeMaxDynamicSharedMemorySize,
                              (16 * M_ * D_ + 64) * 4);

    k0_wqk<<<M_ * DZ_, 256, 0, stream>>>(W_Q, W_K, Wqk);

    dim3 g1(B_ / 64, D_ / 64, M_);
    k1_qk<<<g1, 256, 0, stream>>>(z_anc, Wqk, Qk);

    k2h<<<M_ * B_, 256, 0, stream>>>(h_nei, ew_anc, vmask, lbl_w, Qk, log_vw,
                                     hbar, at_ws);

    k2l<<<B_ * 2, 512, (16 * M_ * D_ + 64) * 4, stream>>>(lbl_delta, at_ws,
                                                          lblp2);

    dim3 g3(B_ / 16, D_ / 64);
    k3_gemm<<<g3, 256, 0, stream>>>(hbar, W_V, lblp2, out);
}